// Round 4
// baseline (185.969 us; speedup 1.0000x reference)
//
#include <hip/hip_runtime.h>
#include <hip/hip_bf16.h>

typedef unsigned short u16;
typedef unsigned int u32;
typedef __bf16 bf16x8 __attribute__((ext_vector_type(8)));
typedef float f32x4 __attribute__((ext_vector_type(4)));

#define N_ROWS 8192
#define DIM 512
#define BM 128
#define BN 128
#define BK 64
#define TEMP_INV (1.0f / 0.07f)

// round-to-nearest-even float -> bf16 bit pattern
__device__ __forceinline__ u16 f2bf(float f) {
    union { float f; u32 u; } a;
    a.f = f;
    u32 r = a.u + 0x7FFFu + ((a.u >> 16) & 1u);
    return (u16)(r >> 16);
}

// ---------------- kernel 1: L2-normalize rows -> bf16; zero accumulators ---
__global__ __launch_bounds__(256) void norm_cast_kernel(
        const float* __restrict__ x, u16* __restrict__ hb,
        float* __restrict__ acc0 /* rowTotal||rowPos, 16384 floats */) {
    if (blockIdx.x < 64) acc0[blockIdx.x * 256 + threadIdx.x] = 0.f;
    int row  = blockIdx.x * 4 + (threadIdx.x >> 6);
    int lane = threadIdx.x & 63;
    const float4* xr = (const float4*)(x + (size_t)row * DIM);
    float4 v0 = xr[lane * 2 + 0];
    float4 v1 = xr[lane * 2 + 1];
    float ss = v0.x * v0.x + v0.y * v0.y + v0.z * v0.z + v0.w * v0.w
             + v1.x * v1.x + v1.y * v1.y + v1.z * v1.z + v1.w * v1.w;
#pragma unroll
    for (int off = 32; off; off >>= 1) ss += __shfl_xor(ss, off);
    float s = 1.0f / fmaxf(sqrtf(ss), 1e-12f);
    uint4 o;
    o.x = (u32)f2bf(v0.x * s) | ((u32)f2bf(v0.y * s) << 16);
    o.y = (u32)f2bf(v0.z * s) | ((u32)f2bf(v0.w * s) << 16);
    o.z = (u32)f2bf(v1.x * s) | ((u32)f2bf(v1.y * s) << 16);
    o.w = (u32)f2bf(v1.z * s) | ((u32)f2bf(v1.w * s) << 16);
    ((uint4*)(hb + (size_t)row * DIM))[lane] = o;
}

// ---------------- kernel 2: triangular fused tile GEMM + exp + sums --------
// Rectangular 64x64 grid with R2's decode (bi>>6, bi&63) so that live blocks
// keep bi = tj (mod 8): round-robin dispatch pins each XCD to 8 B-column
// tiles (~1 MB, L2-resident). Blocks with ti > tj exit before any memory op.
// Off-diagonal tiles emit column sums (-> rows of tj) AND row sums
// (-> rows of ti, via sim(i,j)=sim(j,i)); diagonal tiles column sums only.
__global__ __launch_bounds__(256) void tile_kernel(
        const u16* __restrict__ hb, const int* __restrict__ labels,
        float* __restrict__ rowTotal, float* __restrict__ rowPos) {
    __shared__ __align__(16) u16 ldsA[BM * BK];
    __shared__ __align__(16) u16 ldsB[BN * BK];
    __shared__ int labR[BM];
    __shared__ int labC[BN];
    __shared__ float cT[2][BN], cP[2][BN];   // per wave-row column sums
    __shared__ float rT[2][BM], rP[2][BM];   // per wave-col row sums

    const int bi = blockIdx.x;
    const int ti = bi >> 6;
    const int tj = bi & 63;
    if (ti > tj) return;                     // triangular early-exit
    const int rowBase = ti * BM;
    const int colBase = tj * BN;
    const bool isDiag = (ti == tj);
    const int dd = colBase - rowBase;        // diag element iff rloc - cloc == dd
    const int tid = threadIdx.x;

    if (tid < 128) labR[tid] = labels[rowBase + tid];
    else           labC[tid - 128] = labels[colBase + tid - 128];

    const int w = tid >> 6;
    const int lane = tid & 63;
    const int wm = (w >> 1) * 64;   // wave row offset in tile
    const int wn = (w & 1) * 64;    // wave col offset in tile
    const int wr = w >> 1;          // wave-row id (for cT/cP slot)
    const int wc = w & 1;           // wave-col id (for rT/rP slot)
    const int quad = lane >> 4;
    const int l16 = lane & 15;
    const int sw = l16 & 7;         // xor-swizzle key

    f32x4 acc[4][4];
#pragma unroll
    for (int i = 0; i < 4; ++i)
#pragma unroll
        for (int j = 0; j < 4; ++j)
            acc[i][j] = (f32x4){0.f, 0.f, 0.f, 0.f};

    for (int k0 = 0; k0 < DIM; k0 += BK) {
        // stage tiles; 16 B chunks xor-swizzled within each 128 B row
#pragma unroll
        for (int s = 0; s < 4; ++s) {
            int seg = tid + s * 256;          // 0..1023
            int r = seg >> 3;                 // 0..127
            int c8 = seg & 7;                 // chunk slot in LDS
            int gc = (k0 >> 3) + (c8 ^ (r & 7));
            const u16* ga = hb + (size_t)(rowBase + r) * DIM + gc * 8;
            const u16* gb = hb + (size_t)(colBase + r) * DIM + gc * 8;
            __builtin_amdgcn_global_load_lds(
                (const __attribute__((address_space(1))) void*)ga,
                (__attribute__((address_space(3))) void*)&ldsA[seg * 8], 16, 0, 0);
            __builtin_amdgcn_global_load_lds(
                (const __attribute__((address_space(1))) void*)gb,
                (__attribute__((address_space(3))) void*)&ldsB[seg * 8], 16, 0, 0);
        }
        __syncthreads();
#pragma unroll
        for (int kk8 = 0; kk8 < 8; kk8 += 4) {   // two K=32 steps
            bf16x8 af[4], bfr[4];
#pragma unroll
            for (int im = 0; im < 4; ++im)
                af[im] = *(const bf16x8*)
                    &ldsA[(wm + im * 16 + l16) * BK + (((kk8 + quad) ^ sw) * 8)];
#pragma unroll
            for (int in = 0; in < 4; ++in)
                bfr[in] = *(const bf16x8*)
                    &ldsB[(wn + in * 16 + l16) * BK + (((kk8 + quad) ^ sw) * 8)];
#pragma unroll
            for (int im = 0; im < 4; ++im)
#pragma unroll
                for (int in = 0; in < 4; ++in)
                    acc[im][in] = __builtin_amdgcn_mfma_f32_16x16x32_bf16(
                        af[im], bfr[in], acc[im][in], 0, 0, 0);
        }
        __syncthreads();
    }

    // ---------------- epilogue ----------------
    // C/D layout: col = l16, row = quad*4 + reg (within each 16x16 frag)
    int lc[4];
#pragma unroll
    for (int in = 0; in < 4; ++in) lc[in] = labC[wn + in * 16 + l16];

    float colT[4] = {0.f, 0.f, 0.f, 0.f}, colP[4] = {0.f, 0.f, 0.f, 0.f};
#pragma unroll
    for (int im = 0; im < 4; ++im) {
        float rowT[4] = {0.f, 0.f, 0.f, 0.f}, rowP[4] = {0.f, 0.f, 0.f, 0.f};
#pragma unroll
        for (int reg = 0; reg < 4; ++reg) {
            int rloc = wm + im * 16 + quad * 4 + reg;
            int li = labR[rloc];
#pragma unroll
            for (int in = 0; in < 4; ++in) {
                int cloc = wn + in * 16 + l16;
                float e = __expf(acc[im][in][reg] * TEMP_INV);
                bool pos = (lc[in] == li) && (rloc - cloc != dd);
                colT[in] += e; rowT[reg] += e;
                if (pos) { colP[in] += e; rowP[reg] += e; }
            }
        }
        if (!isDiag) {
            // reduce rowT/rowP over the 16 l16 lanes
#pragma unroll
            for (int reg = 0; reg < 4; ++reg) {
                float t = rowT[reg], p = rowP[reg];
                t += __shfl_xor(t, 1); t += __shfl_xor(t, 2);
                t += __shfl_xor(t, 4); t += __shfl_xor(t, 8);
                p += __shfl_xor(p, 1); p += __shfl_xor(p, 2);
                p += __shfl_xor(p, 4); p += __shfl_xor(p, 8);
                if (l16 == 0) {
                    int rloc = wm + im * 16 + quad * 4 + reg;
                    rT[wc][rloc] = t;   // distinct rloc per (im,quad,reg)
                    rP[wc][rloc] = p;
                }
            }
        }
    }
    // reduce colT/colP over quads
#pragma unroll
    for (int in = 0; in < 4; ++in) {
        float t = colT[in], p = colP[in];
        t += __shfl_xor(t, 16); t += __shfl_xor(t, 32);
        p += __shfl_xor(p, 16); p += __shfl_xor(p, 32);
        if (quad == 0) {
            int cloc = wn + in * 16 + l16;
            cT[wr][cloc] = t;
            cP[wr][cloc] = p;
        }
    }
    __syncthreads();
    if (tid < 128) {
        atomicAdd(&rowTotal[colBase + tid], cT[0][tid] + cT[1][tid]);
        if (!isDiag) atomicAdd(&rowTotal[rowBase + tid], rT[0][tid] + rT[1][tid]);
    } else {
        int t2 = tid - 128;
        atomicAdd(&rowPos[colBase + t2], cP[0][t2] + cP[1][t2]);
        if (!isDiag) atomicAdd(&rowPos[rowBase + t2], rP[0][t2] + rP[1][t2]);
    }
}

// ---------------- kernel 3: histogram + final loss reduce (1 block) --------
__global__ __launch_bounds__(256) void loss_kernel(
        const int* __restrict__ labels, const float* __restrict__ rowTotal,
        const float* __restrict__ rowPos, float* __restrict__ out) {
    __shared__ int hist[128];
    __shared__ float red[256];
    int tid = threadIdx.x;
    if (tid < 128) hist[tid] = 0;
    __syncthreads();
    for (int i = tid; i < N_ROWS; i += 256)
        atomicAdd(&hist[labels[i] & 127], 1);
    __syncthreads();
    float s = 0.f;
    for (int i = tid; i < N_ROWS; i += 256) {
        float c = (float)(hist[labels[i] & 127] - 1);
        float ps = rowPos[i] / (c + 1e-9f);
        s += logf(ps / rowTotal[i]);
    }
    red[tid] = s;
    __syncthreads();
    for (int st = 128; st; st >>= 1) {
        if (tid < st) red[tid] += red[tid + st];
        __syncthreads();
    }
    if (tid == 0) out[0] = -red[0] / (float)N_ROWS;
}

extern "C" void kernel_launch(void* const* d_in, const int* in_sizes, int n_in,
                              void* d_out, int out_size, void* d_ws, size_t ws_size,
                              hipStream_t stream) {
    const float* hidden = (const float*)d_in[0];
    const int* labels   = (const int*)d_in[1];
    float* out = (float*)d_out;

    char* ws = (char*)d_ws;
    u16* hb = (u16*)ws;                                     // 8192*512*2 = 8 MB
    float* rowTotal = (float*)(ws + (size_t)N_ROWS * DIM * 2);
    float* rowPos   = rowTotal + N_ROWS;

    norm_cast_kernel<<<N_ROWS / 4, 256, 0, stream>>>(hidden, hb, rowTotal);
    tile_kernel<<<64 * 64, 256, 0, stream>>>(hb, labels, rowTotal, rowPos);
    loss_kernel<<<1, 256, 0, stream>>>(labels, rowTotal, rowPos, out);
}

// Round 5
// 176.433 us; speedup vs baseline: 1.0541x; 1.0541x over previous
//
#include <hip/hip_runtime.h>
#include <hip/hip_bf16.h>

typedef unsigned short u16;
typedef unsigned int u32;
typedef __bf16 bf16x8 __attribute__((ext_vector_type(8)));
typedef float f32x4 __attribute__((ext_vector_type(4)));

#define N_ROWS 8192
#define DIM 512
#define BM 128
#define BN 128
#define BK 64
#define NREP 16            // accumulator replicas (kills same-address atomic serialization)
#define TEMP_INV (1.0f / 0.07f)

// round-to-nearest-even float -> bf16 bit pattern
__device__ __forceinline__ u16 f2bf(float f) {
    union { float f; u32 u; } a;
    a.f = f;
    u32 r = a.u + 0x7FFFu + ((a.u >> 16) & 1u);
    return (u16)(r >> 16);
}

// ------- kernel 1: L2-normalize rows -> bf16; zero replicas and out --------
__global__ __launch_bounds__(256) void norm_cast_kernel(
        const float* __restrict__ x, u16* __restrict__ hb,
        float* __restrict__ accR /* rowTotalR||rowPosR: 2*NREP*8192 floats */,
        float* __restrict__ out) {
    int gid = blockIdx.x * 256 + threadIdx.x;
    if (gid < 2 * NREP * N_ROWS) accR[gid] = 0.f;
    if (gid == 0) out[0] = 0.f;
    int row  = blockIdx.x * 4 + (threadIdx.x >> 6);
    int lane = threadIdx.x & 63;
    const float4* xr = (const float4*)(x + (size_t)row * DIM);
    float4 v0 = xr[lane * 2 + 0];
    float4 v1 = xr[lane * 2 + 1];
    float ss = v0.x * v0.x + v0.y * v0.y + v0.z * v0.z + v0.w * v0.w
             + v1.x * v1.x + v1.y * v1.y + v1.z * v1.z + v1.w * v1.w;
#pragma unroll
    for (int off = 32; off; off >>= 1) ss += __shfl_xor(ss, off);
    float s = 1.0f / fmaxf(sqrtf(ss), 1e-12f);
    uint4 o;
    o.x = (u32)f2bf(v0.x * s) | ((u32)f2bf(v0.y * s) << 16);
    o.y = (u32)f2bf(v0.z * s) | ((u32)f2bf(v0.w * s) << 16);
    o.z = (u32)f2bf(v1.x * s) | ((u32)f2bf(v1.y * s) << 16);
    o.w = (u32)f2bf(v1.z * s) | ((u32)f2bf(v1.w * s) << 16);
    ((uint4*)(hb + (size_t)row * DIM))[lane] = o;
}

// ------- kernel 2: triangular fused tile GEMM + exp + sums -----------------
// Rectangular 64x64 grid, decode (bi>>6, bi&63): live blocks keep
// bi = tj (mod 8) -> XCD-pinned B columns (R4: fetch 96->31 MB, proven).
// Accumulate into replica rep=(ti+tj)&15 -> no same-address atomic storms
// (R4 regression: concurrent same-ti-row blocks serialized on rowBase).
__global__ __launch_bounds__(256) void tile_kernel(
        const u16* __restrict__ hb, const int* __restrict__ labels,
        float* __restrict__ rowTotalR, float* __restrict__ rowPosR) {
    __shared__ __align__(16) u16 ldsA[BM * BK];
    __shared__ __align__(16) u16 ldsB[BN * BK];
    __shared__ int labR[BM];
    __shared__ int labC[BN];
    __shared__ float cT[2][BN], cP[2][BN];   // per wave-row column sums
    __shared__ float rT[2][BM], rP[2][BM];   // per wave-col row sums

    const int bi = blockIdx.x;
    const int ti = bi >> 6;
    const int tj = bi & 63;
    if (ti > tj) return;                     // triangular early-exit
    const int rowBase = ti * BM;
    const int colBase = tj * BN;
    const bool isDiag = (ti == tj);
    const int dd = colBase - rowBase;        // diag element iff rloc - cloc == dd
    const int rep = (ti + tj) & (NREP - 1);  // varies along BOTH contention axes
    const int tid = threadIdx.x;

    if (tid < 128) labR[tid] = labels[rowBase + tid];
    else           labC[tid - 128] = labels[colBase + tid - 128];

    const int w = tid >> 6;
    const int lane = tid & 63;
    const int wm = (w >> 1) * 64;   // wave row offset in tile
    const int wn = (w & 1) * 64;    // wave col offset in tile
    const int wr = w >> 1;
    const int wc = w & 1;
    const int quad = lane >> 4;
    const int l16 = lane & 15;
    const int sw = l16 & 7;         // xor-swizzle key

    f32x4 acc[4][4];
#pragma unroll
    for (int i = 0; i < 4; ++i)
#pragma unroll
        for (int j = 0; j < 4; ++j)
            acc[i][j] = (f32x4){0.f, 0.f, 0.f, 0.f};

    for (int k0 = 0; k0 < DIM; k0 += BK) {
        // stage tiles; 16 B chunks xor-swizzled within each 128 B row
#pragma unroll
        for (int s = 0; s < 4; ++s) {
            int seg = tid + s * 256;          // 0..1023
            int r = seg >> 3;                 // 0..127
            int c8 = seg & 7;                 // chunk slot in LDS
            int gc = (k0 >> 3) + (c8 ^ (r & 7));
            const u16* ga = hb + (size_t)(rowBase + r) * DIM + gc * 8;
            const u16* gb = hb + (size_t)(colBase + r) * DIM + gc * 8;
            __builtin_amdgcn_global_load_lds(
                (const __attribute__((address_space(1))) void*)ga,
                (__attribute__((address_space(3))) void*)&ldsA[seg * 8], 16, 0, 0);
            __builtin_amdgcn_global_load_lds(
                (const __attribute__((address_space(1))) void*)gb,
                (__attribute__((address_space(3))) void*)&ldsB[seg * 8], 16, 0, 0);
        }
        __syncthreads();
#pragma unroll
        for (int kk8 = 0; kk8 < 8; kk8 += 4) {   // two K=32 steps
            bf16x8 af[4], bfr[4];
#pragma unroll
            for (int im = 0; im < 4; ++im)
                af[im] = *(const bf16x8*)
                    &ldsA[(wm + im * 16 + l16) * BK + (((kk8 + quad) ^ sw) * 8)];
#pragma unroll
            for (int in = 0; in < 4; ++in)
                bfr[in] = *(const bf16x8*)
                    &ldsB[(wn + in * 16 + l16) * BK + (((kk8 + quad) ^ sw) * 8)];
#pragma unroll
            for (int im = 0; im < 4; ++im)
#pragma unroll
                for (int in = 0; in < 4; ++in)
                    acc[im][in] = __builtin_amdgcn_mfma_f32_16x16x32_bf16(
                        af[im], bfr[in], acc[im][in], 0, 0, 0);
        }
        __syncthreads();
    }

    // ---------------- epilogue ----------------
    // C/D layout: col = l16, row = quad*4 + reg (within each 16x16 frag)
    int lc[4];
#pragma unroll
    for (int in = 0; in < 4; ++in) lc[in] = labC[wn + in * 16 + l16];

    float colT[4] = {0.f, 0.f, 0.f, 0.f}, colP[4] = {0.f, 0.f, 0.f, 0.f};
#pragma unroll
    for (int im = 0; im < 4; ++im) {
        float rowT[4] = {0.f, 0.f, 0.f, 0.f}, rowP[4] = {0.f, 0.f, 0.f, 0.f};
#pragma unroll
        for (int reg = 0; reg < 4; ++reg) {
            int rloc = wm + im * 16 + quad * 4 + reg;
            int li = labR[rloc];
#pragma unroll
            for (int in = 0; in < 4; ++in) {
                int cloc = wn + in * 16 + l16;
                float e = __expf(acc[im][in][reg] * TEMP_INV);
                bool pos = (lc[in] == li) && (rloc - cloc != dd);
                colT[in] += e; rowT[reg] += e;
                if (pos) { colP[in] += e; rowP[reg] += e; }
            }
        }
        if (!isDiag) {
#pragma unroll
            for (int reg = 0; reg < 4; ++reg) {
                float t = rowT[reg], p = rowP[reg];
                t += __shfl_xor(t, 1); t += __shfl_xor(t, 2);
                t += __shfl_xor(t, 4); t += __shfl_xor(t, 8);
                p += __shfl_xor(p, 1); p += __shfl_xor(p, 2);
                p += __shfl_xor(p, 4); p += __shfl_xor(p, 8);
                if (l16 == 0) {
                    int rloc = wm + im * 16 + quad * 4 + reg;
                    rT[wc][rloc] = t;   // distinct rloc per (im,quad,reg)
                    rP[wc][rloc] = p;
                }
            }
        }
    }
#pragma unroll
    for (int in = 0; in < 4; ++in) {
        float t = colT[in], p = colP[in];
        t += __shfl_xor(t, 16); t += __shfl_xor(t, 32);
        p += __shfl_xor(p, 16); p += __shfl_xor(p, 32);
        if (quad == 0) {
            int cloc = wn + in * 16 + l16;
            cT[wr][cloc] = t;
            cP[wr][cloc] = p;
        }
    }
    __syncthreads();
    float* rowTotal = rowTotalR + rep * N_ROWS;
    float* rowPos   = rowPosR   + rep * N_ROWS;
    if (tid < 128) {
        atomicAdd(&rowTotal[colBase + tid], cT[0][tid] + cT[1][tid]);
        if (!isDiag) atomicAdd(&rowTotal[rowBase + tid], rT[0][tid] + rT[1][tid]);
    } else {
        int t2 = tid - 128;
        atomicAdd(&rowPos[colBase + t2], cP[0][t2] + cP[1][t2]);
        if (!isDiag) atomicAdd(&rowPos[rowBase + t2], rP[0][t2] + rP[1][t2]);
    }
}

// ------- kernel 3: fold replicas + histogram + loss (64 blocks) ------------
__global__ __launch_bounds__(256) void reduce_loss_kernel(
        const int* __restrict__ labels, const float* __restrict__ rowTotalR,
        const float* __restrict__ rowPosR, float* __restrict__ out) {
    __shared__ int hist[128];
    __shared__ float red[256];
    int tid = threadIdx.x;
    if (tid < 128) hist[tid] = 0;
    __syncthreads();
    for (int i = tid; i < N_ROWS; i += 256)
        atomicAdd(&hist[labels[i] & 127], 1);
    __syncthreads();
    float s = 0.f;
    if (tid < 128) {
        int row = blockIdx.x * 128 + tid;
        float T = 0.f, P = 0.f;
#pragma unroll
        for (int r = 0; r < NREP; ++r) {
            T += rowTotalR[r * N_ROWS + row];
            P += rowPosR[r * N_ROWS + row];
        }
        float c = (float)(hist[labels[row] & 127] - 1);
        s = logf((P / (c + 1e-9f)) / T);
    }
    red[tid] = s;
    __syncthreads();
    for (int st = 128; st; st >>= 1) {
        if (tid < st) red[tid] += red[tid + st];
        __syncthreads();
    }
    if (tid == 0) atomicAdd(out, -red[0] / (float)N_ROWS);
}

extern "C" void kernel_launch(void* const* d_in, const int* in_sizes, int n_in,
                              void* d_out, int out_size, void* d_ws, size_t ws_size,
                              hipStream_t stream) {
    const float* hidden = (const float*)d_in[0];
    const int* labels   = (const int*)d_in[1];
    float* out = (float*)d_out;

    char* ws = (char*)d_ws;
    u16* hb = (u16*)ws;                                     // 8192*512*2 = 8 MB
    float* rowTotalR = (float*)(ws + (size_t)N_ROWS * DIM * 2);  // 16*8192 f
    float* rowPosR   = rowTotalR + NREP * N_ROWS;                // 16*8192 f

    norm_cast_kernel<<<N_ROWS / 4, 256, 0, stream>>>(hidden, hb, rowTotalR, out);
    tile_kernel<<<64 * 64, 256, 0, stream>>>(hb, labels, rowTotalR, rowPosR);
    reduce_loss_kernel<<<64, 256, 0, stream>>>(labels, rowTotalR, rowPosR, out);
}

// Round 6
// 153.171 us; speedup vs baseline: 1.2141x; 1.1519x over previous
//
#include <hip/hip_runtime.h>
#include <hip/hip_bf16.h>

typedef unsigned short u16;
typedef unsigned int u32;
typedef __bf16 bf16x8 __attribute__((ext_vector_type(8)));
typedef float f32x4 __attribute__((ext_vector_type(4)));

#define N_ROWS 8192
#define DIM 512
#define BM 128              // strip rows (A resident in LDS)
#define BN 128              // tj tile width
#define NREP 8              // accumulator replicas, indexed by sub-block id
#define TEMP_INV (1.0f / 0.07f)

// round-to-nearest-even float -> bf16 bit pattern
__device__ __forceinline__ u16 f2bf(float f) {
    union { float f; u32 u; } a;
    a.f = f;
    u32 r = a.u + 0x7FFFu + ((a.u >> 16) & 1u);
    return (u16)(r >> 16);
}

// ------- kernel 1: L2-normalize rows -> bf16; zero replicas and out --------
__global__ __launch_bounds__(256) void norm_cast_kernel(
        const float* __restrict__ x, u16* __restrict__ hb,
        float* __restrict__ accR /* 2*NREP*N_ROWS floats */,
        float* __restrict__ out) {
    int gid = blockIdx.x * 256 + threadIdx.x;
    if (gid < 2 * NREP * N_ROWS) accR[gid] = 0.f;
    if (gid == 0) out[0] = 0.f;
    int row  = blockIdx.x * 4 + (threadIdx.x >> 6);
    int lane = threadIdx.x & 63;
    const float4* xr = (const float4*)(x + (size_t)row * DIM);
    float4 v0 = xr[lane * 2 + 0];
    float4 v1 = xr[lane * 2 + 1];
    float ss = v0.x * v0.x + v0.y * v0.y + v0.z * v0.z + v0.w * v0.w
             + v1.x * v1.x + v1.y * v1.y + v1.z * v1.z + v1.w * v1.w;
#pragma unroll
    for (int off = 32; off; off >>= 1) ss += __shfl_xor(ss, off);
    float s = 1.0f / fmaxf(sqrtf(ss), 1e-12f);
    uint4 o;
    o.x = (u32)f2bf(v0.x * s) | ((u32)f2bf(v0.y * s) << 16);
    o.y = (u32)f2bf(v0.z * s) | ((u32)f2bf(v0.w * s) << 16);
    o.z = (u32)f2bf(v1.x * s) | ((u32)f2bf(v1.y * s) << 16);
    o.w = (u32)f2bf(v1.z * s) | ((u32)f2bf(v1.w * s) << 16);
    ((uint4*)(hb + (size_t)row * DIM))[lane] = o;
}

// ------- kernel 2: strip-persistent triangular GEMM + fused sums -----------
// 256 blocks, 1/CU (152 KB LDS). Block b: pair p=b>>3 (strips p and 63-p),
// sub s=b&7 takes ~8.1 of the pair's 65 upper-triangle tiles. A-strip (128
// rows x K=512) resident in LDS; B streams in BK=32 chunks (8 KB) through 3
// buffers, prefetch depth 2, manual s_waitcnt vmcnt(2) + raw s_barrier so
// in-flight prefetches survive the barrier. Row sums accumulate in REGISTERS
// across the tj loop (symmetric transpose contribution); col sums per tile
// go to global atomics (replica s). Diagonal tiles: row-register path only.
__global__ __launch_bounds__(256, 1) void strip_kernel(
        const u16* __restrict__ hb, const int* __restrict__ labels,
        float* __restrict__ rowTotalR, float* __restrict__ rowPosR) {
    __shared__ __align__(16) u16 ldsA[BM * DIM];      // 128 KB
    __shared__ __align__(16) u16 ldsB[3][BN * 32];    // 3 x 8 KB

    const int b = blockIdx.x;
    const int p = b >> 3;           // strip pair id, [0,32)
    const int s = b & 7;            // sub-block id -> replica
    const int lo = (65 * s) >> 3;
    const int hi = (65 * (s + 1)) >> 3;
    const int nA = 64 - p;          // tiles in strip p

    const int tid = threadIdx.x;
    const int w = tid >> 6;
    const int lane = tid & 63;
    const int wm = (w >> 1) * 64;   // wave row offset
    const int wn = (w & 1) * 64;    // wave col offset
    const int quad = lane >> 4;
    const int l16 = lane & 15;

    float* rTot = rowTotalR + s * N_ROWS;
    float* rPos = rowPosR   + s * N_ROWS;

    for (int ph = 0; ph < 2; ++ph) {
        int a0, a1, ti, tjs;
        if (ph == 0) { a0 = lo; a1 = hi < nA ? hi : nA; ti = p; tjs = p + a0; }
        else { a0 = lo > nA ? lo : nA; a1 = hi; ti = 63 - p; tjs = ti + (a0 - nA); }
        const int cnt = a1 - a0;
        if (cnt <= 0) continue;
        const int rowBase = ti * BM;

        __syncthreads();   // protect old A / old B bufs from overwrite
        // ---- stage A strip: 128 rows x 512, 16B chunks xor-swizzled low-3
#pragma unroll
        for (int i = 0; i < 32; ++i) {
            int seg = tid + i * 256;          // 0..8191
            int r = seg >> 6;                 // 0..127
            int cp = seg & 63;                // chunk slot in LDS
            int c = (cp & 56) | ((cp ^ r) & 7);
            const u16* g = hb + (size_t)(rowBase + r) * DIM + c * 8;
            __builtin_amdgcn_global_load_lds(
                (const __attribute__((address_space(1))) void*)g,
                (__attribute__((address_space(3))) void*)&ldsA[seg * 8], 16, 0, 0);
        }

        int lr[16];
#pragma unroll
        for (int im = 0; im < 4; ++im)
#pragma unroll
            for (int reg = 0; reg < 4; ++reg)
                lr[im * 4 + reg] = labels[rowBase + wm + im * 16 + quad * 4 + reg];

        float rowTa[16], rowPa[16];
#pragma unroll
        for (int i = 0; i < 16; ++i) { rowTa[i] = 0.f; rowPa[i] = 0.f; }

        for (int t = 0; t < cnt; ++t) {
            const int tj = tjs + t;
            const bool isDiag = (tj == ti);
            const u16* bsrc = hb + (size_t)tj * BM * DIM;

            __syncthreads();  // all waves done with prev tile's bufs (drains A on t=0)

            // prefetch chunks 0,1
#pragma unroll
            for (int kw = 0; kw < 2; ++kw)
#pragma unroll
                for (int s2 = 0; s2 < 2; ++s2) {
                    int seg = tid + s2 * 256;          // 0..511
                    int col = seg >> 2;
                    int c = (seg & 3) ^ (col & 3);
                    const u16* g = bsrc + (size_t)col * DIM + kw * 32 + c * 8;
                    __builtin_amdgcn_global_load_lds(
                        (const __attribute__((address_space(1))) void*)g,
                        (__attribute__((address_space(3))) void*)&ldsB[kw][seg * 8], 16, 0, 0);
                }

            int lc[4];
#pragma unroll
            for (int in = 0; in < 4; ++in)
                lc[in] = labels[tj * BM + wn + in * 16 + l16];

            f32x4 acc[4][4];
#pragma unroll
            for (int i = 0; i < 4; ++i)
#pragma unroll
                for (int j = 0; j < 4; ++j)
                    acc[i][j] = (f32x4){0.f, 0.f, 0.f, 0.f};

#pragma unroll
            for (int kw = 0; kw < 16; ++kw) {
                // wave-local: my chunk-kw loads done (oldest); kw+1 may stay in flight
                if (kw < 15) asm volatile("s_waitcnt vmcnt(2)" ::: "memory");
                else         asm volatile("s_waitcnt vmcnt(0)" ::: "memory");
                asm volatile("s_barrier" ::: "memory");
                if (kw < 14) {
                    const int kn = kw + 2;
#pragma unroll
                    for (int s2 = 0; s2 < 2; ++s2) {
                        int seg = tid + s2 * 256;
                        int col = seg >> 2;
                        int c = (seg & 3) ^ (col & 3);
                        const u16* g = bsrc + (size_t)col * DIM + kn * 32 + c * 8;
                        __builtin_amdgcn_global_load_lds(
                            (const __attribute__((address_space(1))) void*)g,
                            (__attribute__((address_space(3))) void*)&ldsB[kn % 3][seg * 8], 16, 0, 0);
                    }
                }
                // compute chunk kw from buf[kw%3]
                const u16* bb = ldsB[kw % 3];
                bf16x8 af[4], bfr[4];
#pragma unroll
                for (int im = 0; im < 4; ++im) {
                    int row = wm + im * 16 + l16;
                    int ck = (kw * 4 + quad) ^ (row & 7);
                    af[im] = *(const bf16x8*)&ldsA[row * DIM + ck * 8];
                }
#pragma unroll
                for (int in = 0; in < 4; ++in) {
                    int col = wn + in * 16 + l16;
                    int c = quad ^ (col & 3);
                    bfr[in] = *(const bf16x8*)&bb[col * 32 + c * 8];
                }
#pragma unroll
                for (int im = 0; im < 4; ++im)
#pragma unroll
                    for (int in = 0; in < 4; ++in)
                        acc[im][in] = __builtin_amdgcn_mfma_f32_16x16x32_bf16(
                            af[im], bfr[in], acc[im][in], 0, 0, 0);
            }

            // ---- per-tile epilogue: exp, masks, col sums + register row sums
            float colT[4] = {0.f, 0.f, 0.f, 0.f}, colP[4] = {0.f, 0.f, 0.f, 0.f};
#pragma unroll
            for (int im = 0; im < 4; ++im)
#pragma unroll
                for (int reg = 0; reg < 4; ++reg) {
                    int rloc = wm + im * 16 + quad * 4 + reg;
                    int li = lr[im * 4 + reg];
#pragma unroll
                    for (int in = 0; in < 4; ++in) {
                        int cloc = wn + in * 16 + l16;
                        float e = __expf(acc[im][in][reg] * TEMP_INV);
                        bool pos = (lc[in] == li) && !(isDiag && rloc == cloc);
                        colT[in] += e; rowTa[im * 4 + reg] += e;
                        if (pos) { colP[in] += e; rowPa[im * 4 + reg] += e; }
                    }
                }
            if (!isDiag) {
#pragma unroll
                for (int in = 0; in < 4; ++in) {
                    float tt = colT[in], pp = colP[in];
                    tt += __shfl_xor(tt, 16); tt += __shfl_xor(tt, 32);
                    pp += __shfl_xor(pp, 16); pp += __shfl_xor(pp, 32);
                    if (quad == 0) {
                        int gc = tj * BM + wn + in * 16 + l16;
                        atomicAdd(&rTot[gc], tt);
                        atomicAdd(&rPos[gc], pp);
                    }
                }
            }
        }

        // ---- phase end: reduce register row sums over l16, atomic once ----
#pragma unroll
        for (int i = 0; i < 16; ++i) {
            float tt = rowTa[i], pp = rowPa[i];
            tt += __shfl_xor(tt, 1); tt += __shfl_xor(tt, 2);
            tt += __shfl_xor(tt, 4); tt += __shfl_xor(tt, 8);
            pp += __shfl_xor(pp, 1); pp += __shfl_xor(pp, 2);
            pp += __shfl_xor(pp, 4); pp += __shfl_xor(pp, 8);
            if (l16 == 0) {
                int gr = rowBase + wm + (i >> 2) * 16 + quad * 4 + (i & 3);
                atomicAdd(&rTot[gr], tt);
                atomicAdd(&rPos[gr], pp);
            }
        }
    }
}

// ------- kernel 3: fold replicas + histogram + loss (64 blocks) ------------
__global__ __launch_bounds__(256) void reduce_loss_kernel(
        const int* __restrict__ labels, const float* __restrict__ rowTotalR,
        const float* __restrict__ rowPosR, float* __restrict__ out) {
    __shared__ int hist[128];
    __shared__ float red[256];
    int tid = threadIdx.x;
    if (tid < 128) hist[tid] = 0;
    __syncthreads();
    for (int i = tid; i < N_ROWS; i += 256)
        atomicAdd(&hist[labels[i] & 127], 1);
    __syncthreads();
    float sacc = 0.f;
    if (tid < 128) {
        int row = blockIdx.x * 128 + tid;
        float T = 0.f, P = 0.f;
#pragma unroll
        for (int r = 0; r < NREP; ++r) {
            T += rowTotalR[r * N_ROWS + row];
            P += rowPosR[r * N_ROWS + row];
        }
        float c = (float)(hist[labels[row] & 127] - 1);
        sacc = logf((P / (c + 1e-9f)) / T);
    }
    red[tid] = sacc;
    __syncthreads();
    for (int st = 128; st; st >>= 1) {
        if (tid < st) red[tid] += red[tid + st];
        __syncthreads();
    }
    if (tid == 0) atomicAdd(out, -red[0] / (float)N_ROWS);
}

extern "C" void kernel_launch(void* const* d_in, const int* in_sizes, int n_in,
                              void* d_out, int out_size, void* d_ws, size_t ws_size,
                              hipStream_t stream) {
    const float* hidden = (const float*)d_in[0];
    const int* labels   = (const int*)d_in[1];
    float* out = (float*)d_out;

    char* ws = (char*)d_ws;
    u16* hb = (u16*)ws;                                          // 8 MB
    float* rowTotalR = (float*)(ws + (size_t)N_ROWS * DIM * 2);  // NREP*8192 f
    float* rowPosR   = rowTotalR + NREP * N_ROWS;                // NREP*8192 f

    norm_cast_kernel<<<N_ROWS / 4, 256, 0, stream>>>(hidden, hb, rowTotalR, out);
    strip_kernel<<<256, 256, 0, stream>>>(hb, labels, rowTotalR, rowPosR);
    reduce_loss_kernel<<<64, 256, 0, stream>>>(labels, rowTotalR, rowPosR, out);
}